// Round 4
// baseline (739.280 us; speedup 1.0000x reference)
//
#include <hip/hip_runtime.h>
#include <cmath>

// CausalSelfAttention fused pipeline, MI355X/gfx950.
// R4: fp32 I/O, *fp16* internal compute (8x smaller rounding than bf16,
// same MFMA rate; all values range-bounded inside fp16).
// Stages: [f32->f16 convert] -> [gemm q,k,v] -> [rmsnorm+rope+gain relayout]
//         -> [flash attn MFMA] -> [gemm out, fp32 epilogue].

#define S_LEN 2048
#define DMODEL 2048
#define NH 16
#define NKV 4
#define HD 128

#define NEG_SENT -1.0e30f

typedef _Float16 f16x8 __attribute__((ext_vector_type(8)));
typedef short short8 __attribute__((ext_vector_type(8)));
typedef float f32x4 __attribute__((ext_vector_type(4)));

static __device__ __forceinline__ short f2h(float f) {
  _Float16 h = (_Float16)f;
  return *(short*)&h;
}
static __device__ __forceinline__ float h2f(short s) {
  _Float16 h = *(_Float16*)&s;
  return (float)h;
}

// ---------------------------------------------------------------------------
// fp32 -> fp16 elementwise convert (n divisible by 4).
// ---------------------------------------------------------------------------
__global__ __launch_bounds__(256) void f32_to_f16(const float* __restrict__ src,
                                                  short* __restrict__ dst, int n) {
  int i = (blockIdx.x * 256 + threadIdx.x) * 4;
  if (i < n) {
    float4 v = *reinterpret_cast<const float4*>(src + i);
    short4 o;
    o.x = f2h(v.x); o.y = f2h(v.y); o.z = f2h(v.z); o.w = f2h(v.w);
    *reinterpret_cast<short4*>(dst + i) = o;
  }
}

// ---------------------------------------------------------------------------
// GEMM: C[M,N] = A[M,K] @ W[N,K]^T, fp16 in, fp32 accum, fp16 or fp32 out.
// 128x128 block tile, BK=64, 4 waves x (4x4 grid of 16x16x32 MFMAs).
// LDS rows padded to 72 halves.
// ---------------------------------------------------------------------------
template <bool F32OUT>
__global__ __launch_bounds__(256) void gemm_bt(const short* __restrict__ A,
                                               const short* __restrict__ W,
                                               void* __restrict__ Cv,
                                               int M, int N, int K) {
  __shared__ short As[128][72];
  __shared__ short Ws[128][72];
  const int tid = threadIdx.x;
  const int wave = tid >> 6, lane = tid & 63;
  const int quad = lane >> 4, l16 = lane & 15;
  const int bm = blockIdx.x * 128, bn = blockIdx.y * 128;
  const int wm = (wave >> 1) * 64, wn = (wave & 1) * 64;

  f32x4 acc[4][4];
#pragma unroll
  for (int i = 0; i < 4; i++)
#pragma unroll
    for (int j = 0; j < 4; j++) acc[i][j] = f32x4{0.f, 0.f, 0.f, 0.f};

  const int lrow = tid >> 3;        // 0..31
  const int lcol = (tid & 7) * 8;   // 0..56 step 8

  for (int k0 = 0; k0 < K; k0 += 64) {
    __syncthreads();
#pragma unroll
    for (int i = 0; i < 4; i++) {
      int r = lrow + i * 32;
      *reinterpret_cast<int4*>(&As[r][lcol]) =
          *reinterpret_cast<const int4*>(A + (size_t)(bm + r) * K + k0 + lcol);
      *reinterpret_cast<int4*>(&Ws[r][lcol]) =
          *reinterpret_cast<const int4*>(W + (size_t)(bn + r) * K + k0 + lcol);
    }
    __syncthreads();
#pragma unroll
    for (int kk = 0; kk < 64; kk += 32) {
      f16x8 af[4], bfr[4];
#pragma unroll
      for (int mi = 0; mi < 4; mi++)
        af[mi] = *reinterpret_cast<const f16x8*>(&As[wm + mi * 16 + l16][kk + quad * 8]);
#pragma unroll
      for (int ni = 0; ni < 4; ni++)
        bfr[ni] = *reinterpret_cast<const f16x8*>(&Ws[wn + ni * 16 + l16][kk + quad * 8]);
#pragma unroll
      for (int mi = 0; mi < 4; mi++)
#pragma unroll
        for (int ni = 0; ni < 4; ni++)
          acc[mi][ni] = __builtin_amdgcn_mfma_f32_16x16x32_f16(af[mi], bfr[ni], acc[mi][ni], 0, 0, 0);
    }
  }
  // C/D layout: row = quad*4 + r, col = l16
#pragma unroll
  for (int mi = 0; mi < 4; mi++)
#pragma unroll
    for (int ni = 0; ni < 4; ni++) {
      int gr = bm + wm + mi * 16 + quad * 4;
      int gc = bn + wn + ni * 16 + l16;
#pragma unroll
      for (int r = 0; r < 4; r++) {
        if (F32OUT)
          ((float*)Cv)[(size_t)(gr + r) * N + gc] = acc[mi][ni][r];
        else
          ((short*)Cv)[(size_t)(gr + r) * N + gc] = f2h(acc[mi][ni][r]);
      }
    }
}

// ---------------------------------------------------------------------------
// Per-(token,head) RMSNorm + partial RoPE + optional gain, relayout to
// [b][head][s][128] fp16. One wave per (token, head); lane holds dims
// {lane, lane+64}. mode: 1=norm+rope(k), 2=norm+rope+gain(q).
// ---------------------------------------------------------------------------
__global__ __launch_bounds__(256) void postproc(const short* __restrict__ src,
                                                short* __restrict__ dst,
                                                const float* __restrict__ gain,
                                                int n_heads, int mode) {
  int gw = blockIdx.x * 4 + (threadIdx.x >> 6);
  int lane = threadIdx.x & 63;
  int head = gw % n_heads;
  int token = gw / n_heads;
  int s = token & (S_LEN - 1);
  int b = token >> 11;
  const short* sp = src + (size_t)token * (n_heads * HD) + head * HD;
  float v0 = h2f(sp[lane]);
  float v1 = h2f(sp[lane + 64]);
  float ss = v0 * v0 + v1 * v1;
#pragma unroll
  for (int off = 1; off < 64; off <<= 1) ss += __shfl_xor(ss, off, 64);
  float sc = rsqrtf(ss * (1.0f / 128.0f) + 1.1920929e-07f);
  v0 *= sc;
  v1 *= sc;
  // RoPE on dims [0,64): pair (i, i+32), angle = s * 10000^(-2i/64)
  int i = lane & 31;
  float inv = powf(10000.0f, -((float)(2 * i) * (1.0f / 64.0f)));
  float f = (float)s * inv;
  float cs, sn;
  sincosf(f, &sn, &cs);
  float partner = __shfl_xor(v0, 32, 64);
  v0 = (lane < 32) ? (v0 * cs + partner * sn) : (v0 * cs - partner * sn);
  if (mode == 2) {
    float g = gain[head];
    v0 *= g;
    v1 *= g;
  }
  short* dp = dst + ((size_t)(b * n_heads + head) * S_LEN + s) * HD;
  dp[lane] = f2h(v0);
  dp[lane + 64] = f2h(v1);
}

// ---------------------------------------------------------------------------
// Flash-style causal attention (fp16 fragments, fp32 softmax/accum).
// Block = 4 waves; wave w handles 16 queries. K tiles of 32 staged in LDS
// row-major; V read token-major ([token][512], head slice) and staged
// transposed. P goes through per-wave padded LDS (C-layout -> A-layout).
// Uniform tile count per block so __syncthreads is safe. Finite sentinels.
// ---------------------------------------------------------------------------
__global__ __launch_bounds__(256) void attn_fwd(const short* __restrict__ qb,
                                                const short* __restrict__ kb,
                                                const short* __restrict__ vtok,
                                                short* __restrict__ out) {
  __shared__ short k_lds[32][136];   // [key][dim], pad 8
  __shared__ short vt_lds[128][40];  // [dim][key], pad 8
  __shared__ short p_lds[4][16][40]; // per-wave [query][key], pad 8

  const int tid = threadIdx.x, wave = tid >> 6, lane = tid & 63;
  const int quad = lane >> 4, l16 = lane & 15;
  const int bh = blockIdx.y;
  const int b = bh >> 4, h = bh & 15;
  const int kvh = h >> 2;
  const int q0blk = blockIdx.x * 64;
  const int q0 = q0blk + wave * 16;

  const short* qptr = qb + ((size_t)(b * NH + h) * S_LEN + q0) * HD;
  const short* kptr = kb + ((size_t)(b * NKV + kvh) * S_LEN) * HD;
  const short* vptr = vtok + (size_t)(b * S_LEN) * (NKV * HD) + kvh * HD;

  // Q fragments: A-layout, m = l16, k = st*32 + quad*8 + j
  f16x8 qf[4];
#pragma unroll
  for (int st = 0; st < 4; st++)
    qf[st] = *reinterpret_cast<const f16x8*>(qptr + l16 * HD + st * 32 + quad * 8);

  f32x4 o[8];
#pragma unroll
  for (int i = 0; i < 8; i++) o[i] = f32x4{0.f, 0.f, 0.f, 0.f};
  float m_i[4] = {NEG_SENT, NEG_SENT, NEG_SENT, NEG_SENT};
  float l_i[4] = {0.f, 0.f, 0.f, 0.f};
  const float scale = 0.08838834764831845f;  // 1/sqrt(128)

  const int ktiles = q0blk / 32 + 2;  // keys 0 .. q0blk+63
  for (int kt = 0; kt < ktiles; kt++) {
    const int kbase = kt * 32;
    __syncthreads();
    // stage K (row-major) and V (transposed; V is token-major stride 512)
#pragma unroll
    for (int i = 0; i < 2; i++) {
      int idx = tid + i * 256;      // 0..511
      int row = idx >> 4;           // key 0..31
      int col = (idx & 15) * 8;     // dim 0..120
      *reinterpret_cast<int4*>(&k_lds[row][col]) =
          *reinterpret_cast<const int4*>(kptr + (size_t)(kbase + row) * HD + col);
      short8 vv = *reinterpret_cast<const short8*>(
          vptr + (size_t)(kbase + row) * (NKV * HD) + col);
#pragma unroll
      for (int j = 0; j < 8; j++) vt_lds[col + j][row] = vv[j];
    }
    __syncthreads();

    // S = Q K^T : two 16x16 column tiles (keys 0-15, 16-31)
    f32x4 sc0 = f32x4{0.f, 0.f, 0.f, 0.f};
    f32x4 sc1 = f32x4{0.f, 0.f, 0.f, 0.f};
#pragma unroll
    for (int st = 0; st < 4; st++) {
      f16x8 kf0 = *reinterpret_cast<const f16x8*>(&k_lds[l16][st * 32 + quad * 8]);
      f16x8 kf1 = *reinterpret_cast<const f16x8*>(&k_lds[16 + l16][st * 32 + quad * 8]);
      sc0 = __builtin_amdgcn_mfma_f32_16x16x32_f16(qf[st], kf0, sc0, 0, 0, 0);
      sc1 = __builtin_amdgcn_mfma_f32_16x16x32_f16(qf[st], kf1, sc1, 0, 0, 0);
    }

    // scale + causal mask + online softmax (row r lives at quad*4+r)
    float rowmax[4], rowsum[4];
#pragma unroll
    for (int r = 0; r < 4; r++) {
      int qrow = q0 + quad * 4 + r;
      float s0 = (kbase + l16 <= qrow) ? sc0[r] * scale : NEG_SENT;
      float s1 = (kbase + 16 + l16 <= qrow) ? sc1[r] * scale : NEG_SENT;
      sc0[r] = s0;
      sc1[r] = s1;
      rowmax[r] = fmaxf(s0, s1);
    }
#pragma unroll
    for (int off = 1; off < 16; off <<= 1)
#pragma unroll
      for (int r = 0; r < 4; r++)
        rowmax[r] = fmaxf(rowmax[r], __shfl_xor(rowmax[r], off, 64));

    float alpha[4];
#pragma unroll
    for (int r = 0; r < 4; r++) {
      float mnew = fmaxf(m_i[r], rowmax[r]);
      alpha[r] = __expf(fminf(m_i[r] - mnew, 0.f));
      m_i[r] = mnew;
    }
#pragma unroll
    for (int r = 0; r < 4; r++) {
      float p0 = __expf(fminf(sc0[r] - m_i[r], 0.f));
      float p1 = __expf(fminf(sc1[r] - m_i[r], 0.f));
      if (sc0[r] == NEG_SENT) p0 = 0.f;
      if (sc1[r] == NEG_SENT) p1 = 0.f;
      rowsum[r] = p0 + p1;
      p_lds[wave][quad * 4 + r][l16] = f2h(p0);
      p_lds[wave][quad * 4 + r][16 + l16] = f2h(p1);
    }
#pragma unroll
    for (int off = 1; off < 16; off <<= 1)
#pragma unroll
      for (int r = 0; r < 4; r++) rowsum[r] += __shfl_xor(rowsum[r], off, 64);
#pragma unroll
    for (int r = 0; r < 4; r++) l_i[r] = l_i[r] * alpha[r] + rowsum[r];
#pragma unroll
    for (int nt = 0; nt < 8; nt++)
#pragma unroll
      for (int r = 0; r < 4; r++) o[nt][r] *= alpha[r];

    __syncthreads();  // publish p_lds (uniform trip count -> safe)

    // O += P V : P in A-layout (m=l16, k=quad*8+j), V^T rows give B-frags
    f16x8 pf = *reinterpret_cast<const f16x8*>(&p_lds[wave][l16][quad * 8]);
#pragma unroll
    for (int nt = 0; nt < 8; nt++) {
      f16x8 vf = *reinterpret_cast<const f16x8*>(&vt_lds[nt * 16 + l16][quad * 8]);
      o[nt] = __builtin_amdgcn_mfma_f32_16x16x32_f16(pf, vf, o[nt], 0, 0, 0);
    }
  }

#pragma unroll
  for (int r = 0; r < 4; r++) l_i[r] = 1.0f / fmaxf(l_i[r], 1e-20f);
#pragma unroll
  for (int nt = 0; nt < 8; nt++)
#pragma unroll
    for (int r = 0; r < 4; r++) {
      int srow = q0 + quad * 4 + r;
      int dcol = nt * 16 + l16;
      out[((size_t)(b * S_LEN + srow)) * DMODEL + h * HD + dcol] =
          f2h(o[nt][r] * l_i[r]);
    }
}

extern "C" void kernel_launch(void* const* d_in, const int* in_sizes, int n_in,
                              void* d_out, int out_size, void* d_ws, size_t ws_size,
                              hipStream_t stream) {
  const float* x      = (const float*)d_in[0];  // [2,2048,2048] fp32
  const float* q_w    = (const float*)d_in[1];  // [2048,2048]
  const float* k_w    = (const float*)d_in[2];  // [512,2048]
  const float* v_w    = (const float*)d_in[3];  // [512,2048]
  const float* out_w  = (const float*)d_in[4];  // [2048,2048]
  const float* q_gain = (const float*)d_in[5];  // [16]
  float* out = (float*)d_out;                   // [2,2048,2048] fp32

  const int BS = 2 * S_LEN;  // 4096 tokens
  // ws layout in fp16 shorts. Peak 80 MB. attn aliases qraw (dead by then).
  short* xb   = (short*)d_ws;                    // 8M  (16MB)
  short* wqb  = xb   + (size_t)8 * 1024 * 1024;  // 4M  ( 8MB)
  short* wkb  = wqb  + (size_t)4 * 1024 * 1024;  // 1M  ( 2MB)
  short* wvb  = wkb  + (size_t)1 * 1024 * 1024;  // 1M  ( 2MB)
  short* wob  = wvb  + (size_t)1 * 1024 * 1024;  // 4M  ( 8MB)
  short* qraw = wob  + (size_t)4 * 1024 * 1024;  // 8M  (16MB)
  short* kraw = qraw + (size_t)8 * 1024 * 1024;  // 2M  ( 4MB)
  short* vraw = kraw + (size_t)2 * 1024 * 1024;  // 2M  ( 4MB) token-major V
  short* qb   = vraw + (size_t)2 * 1024 * 1024;  // 8M  (16MB)
  short* kbuf = qb   + (size_t)8 * 1024 * 1024;  // 2M  ( 4MB)
  short* attn = qraw;                            // alias

  dim3 blk(256);
  f32_to_f16<<<8192, blk, 0, stream>>>(x, xb, BS * DMODEL);
  f32_to_f16<<<4096, blk, 0, stream>>>(q_w, wqb, DMODEL * DMODEL);
  f32_to_f16<<<1024, blk, 0, stream>>>(k_w, wkb, 512 * DMODEL);
  f32_to_f16<<<1024, blk, 0, stream>>>(v_w, wvb, 512 * DMODEL);
  f32_to_f16<<<4096, blk, 0, stream>>>(out_w, wob, DMODEL * DMODEL);

  gemm_bt<false><<<dim3(32, 16), blk, 0, stream>>>(xb, wqb, qraw, 4096, 2048, 2048);
  gemm_bt<false><<<dim3(32, 4), blk, 0, stream>>>(xb, wkb, kraw, 4096, 512, 2048);
  gemm_bt<false><<<dim3(32, 4), blk, 0, stream>>>(xb, wvb, vraw, 4096, 512, 2048);

  postproc<<<dim3((BS * NH) / 4), blk, 0, stream>>>(qraw, qb, q_gain, NH, 2);
  postproc<<<dim3((BS * NKV) / 4), blk, 0, stream>>>(kraw, kbuf, q_gain, NKV, 1);

  attn_fwd<<<dim3(S_LEN / 64, 2 * NH), blk, 0, stream>>>(qb, kbuf, vraw, attn);

  gemm_bt<true><<<dim3(32, 16), blk, 0, stream>>>(attn, wob, out, 4096, 2048, 2048);
}

// Round 6
// 534.211 us; speedup vs baseline: 1.3839x; 1.3839x over previous
//
#include <hip/hip_runtime.h>
#include <cmath>

// CausalSelfAttention fused pipeline, MI355X/gfx950.
// R6: fix R5's K-staging bug (only dims 0..63 were staged). Attention:
// BQ=128/BK=64, global V^T, 2 barriers/tile, balanced dispatch.

#define S_LEN 2048
#define DMODEL 2048
#define NH 16
#define NKV 4
#define HD 128

#define NEG_SENT -1.0e30f

typedef _Float16 f16x8 __attribute__((ext_vector_type(8)));
typedef float f32x4 __attribute__((ext_vector_type(4)));

static __device__ __forceinline__ short f2h(float f) {
  _Float16 h = (_Float16)f;
  return *(short*)&h;
}
static __device__ __forceinline__ float h2f(short s) {
  _Float16 h = *(_Float16*)&s;
  return (float)h;
}

// ---------------------------------------------------------------------------
// fp32 -> fp16 elementwise convert (n divisible by 4).
// ---------------------------------------------------------------------------
__global__ __launch_bounds__(256) void f32_to_f16(const float* __restrict__ src,
                                                  short* __restrict__ dst, int n) {
  int i = (blockIdx.x * 256 + threadIdx.x) * 4;
  if (i < n) {
    float4 v = *reinterpret_cast<const float4*>(src + i);
    short4 o;
    o.x = f2h(v.x); o.y = f2h(v.y); o.z = f2h(v.z); o.w = f2h(v.w);
    *reinterpret_cast<short4*>(dst + i) = o;
  }
}

// ---------------------------------------------------------------------------
// GEMM: C[M,N] = A[M,K] @ W[N,K]^T, fp16 in, fp32 accum, fp16 or fp32 out.
// ---------------------------------------------------------------------------
template <bool F32OUT>
__global__ __launch_bounds__(256) void gemm_bt(const short* __restrict__ A,
                                               const short* __restrict__ W,
                                               void* __restrict__ Cv,
                                               int M, int N, int K) {
  __shared__ __align__(16) short As[128][72];
  __shared__ __align__(16) short Ws[128][72];
  const int tid = threadIdx.x;
  const int wave = tid >> 6, lane = tid & 63;
  const int quad = lane >> 4, l16 = lane & 15;
  const int bm = blockIdx.x * 128, bn = blockIdx.y * 128;
  const int wm = (wave >> 1) * 64, wn = (wave & 1) * 64;

  f32x4 acc[4][4];
#pragma unroll
  for (int i = 0; i < 4; i++)
#pragma unroll
    for (int j = 0; j < 4; j++) acc[i][j] = f32x4{0.f, 0.f, 0.f, 0.f};

  const int lrow = tid >> 3;
  const int lcol = (tid & 7) * 8;

  for (int k0 = 0; k0 < K; k0 += 64) {
    __syncthreads();
#pragma unroll
    for (int i = 0; i < 4; i++) {
      int r = lrow + i * 32;
      *reinterpret_cast<int4*>(&As[r][lcol]) =
          *reinterpret_cast<const int4*>(A + (size_t)(bm + r) * K + k0 + lcol);
      *reinterpret_cast<int4*>(&Ws[r][lcol]) =
          *reinterpret_cast<const int4*>(W + (size_t)(bn + r) * K + k0 + lcol);
    }
    __syncthreads();
#pragma unroll
    for (int kk = 0; kk < 64; kk += 32) {
      f16x8 af[4], bfr[4];
#pragma unroll
      for (int mi = 0; mi < 4; mi++)
        af[mi] = *reinterpret_cast<const f16x8*>(&As[wm + mi * 16 + l16][kk + quad * 8]);
#pragma unroll
      for (int ni = 0; ni < 4; ni++)
        bfr[ni] = *reinterpret_cast<const f16x8*>(&Ws[wn + ni * 16 + l16][kk + quad * 8]);
#pragma unroll
      for (int mi = 0; mi < 4; mi++)
#pragma unroll
        for (int ni = 0; ni < 4; ni++)
          acc[mi][ni] = __builtin_amdgcn_mfma_f32_16x16x32_f16(af[mi], bfr[ni], acc[mi][ni], 0, 0, 0);
    }
  }
#pragma unroll
  for (int mi = 0; mi < 4; mi++)
#pragma unroll
    for (int ni = 0; ni < 4; ni++) {
      int gr = bm + wm + mi * 16 + quad * 4;
      int gc = bn + wn + ni * 16 + l16;
#pragma unroll
      for (int r = 0; r < 4; r++) {
        if (F32OUT)
          ((float*)Cv)[(size_t)(gr + r) * N + gc] = acc[mi][ni][r];
        else
          ((short*)Cv)[(size_t)(gr + r) * N + gc] = f2h(acc[mi][ni][r]);
      }
    }
}

// ---------------------------------------------------------------------------
// Per-(token,head) RMSNorm + partial RoPE + optional gain, relayout to
// [b][head][s][128]. mode: 1=norm+rope(k), 2=norm+rope+gain(q).
// ---------------------------------------------------------------------------
__global__ __launch_bounds__(256) void postproc(const short* __restrict__ src,
                                                short* __restrict__ dst,
                                                const float* __restrict__ gain,
                                                int n_heads, int mode) {
  int gw = blockIdx.x * 4 + (threadIdx.x >> 6);
  int lane = threadIdx.x & 63;
  int head = gw % n_heads;
  int token = gw / n_heads;
  int s = token & (S_LEN - 1);
  int b = token >> 11;
  const short* sp = src + (size_t)token * (n_heads * HD) + head * HD;
  float v0 = h2f(sp[lane]);
  float v1 = h2f(sp[lane + 64]);
  float ss = v0 * v0 + v1 * v1;
#pragma unroll
  for (int off = 1; off < 64; off <<= 1) ss += __shfl_xor(ss, off, 64);
  float sc = rsqrtf(ss * (1.0f / 128.0f) + 1.1920929e-07f);
  v0 *= sc;
  v1 *= sc;
  int i = lane & 31;
  float inv = powf(10000.0f, -((float)(2 * i) * (1.0f / 64.0f)));
  float f = (float)s * inv;
  float cs, sn;
  sincosf(f, &sn, &cs);
  float partner = __shfl_xor(v0, 32, 64);
  v0 = (lane < 32) ? (v0 * cs + partner * sn) : (v0 * cs - partner * sn);
  if (mode == 2) {
    float g = gain[head];
    v0 *= g;
    v1 *= g;
  }
  short* dp = dst + ((size_t)(b * n_heads + head) * S_LEN + s) * HD;
  dp[lane] = f2h(v0);
  dp[lane + 64] = f2h(v1);
}

// ---------------------------------------------------------------------------
// Tiled transpose: vraw[token][512] -> vT[b][kv][dim128][seq2048].
// ---------------------------------------------------------------------------
__global__ __launch_bounds__(256) void v_transpose(const short* __restrict__ src,
                                                   short* __restrict__ dst) {
  __shared__ __align__(16) short t[64][72];
  const int tid = threadIdx.x;
  const int s0 = blockIdx.x * 64;   // token tile (64 | 2048 so b uniform)
  const int d0 = blockIdx.y * 64;   // dim tile
#pragma unroll
  for (int i = 0; i < 2; i++) {
    int r = (tid >> 3) + i * 32;        // seq in tile
    int c = (tid & 7) * 8;              // dim in tile
    *reinterpret_cast<int4*>(&t[r][c]) =
        *reinterpret_cast<const int4*>(src + (size_t)(s0 + r) * 512 + d0 + c);
  }
  __syncthreads();
  const int b = s0 >> 11;
  const int sbase = s0 & (S_LEN - 1);
#pragma unroll
  for (int i = 0; i < 2; i++) {
    int dr = (tid >> 3) + i * 32;       // dim in tile
    int sc8 = (tid & 7) * 8;            // seq in tile
    int d = d0 + dr;
    int kv = d >> 7, dw = d & 127;
    short4 lo, hi;
    lo.x = t[sc8 + 0][dr]; lo.y = t[sc8 + 1][dr];
    lo.z = t[sc8 + 2][dr]; lo.w = t[sc8 + 3][dr];
    hi.x = t[sc8 + 4][dr]; hi.y = t[sc8 + 5][dr];
    hi.z = t[sc8 + 6][dr]; hi.w = t[sc8 + 7][dr];
    short* dp = dst + (((size_t)(b * NKV + kv) * HD + dw) * S_LEN) + sbase + sc8;
    *reinterpret_cast<short4*>(dp) = lo;
    *reinterpret_cast<short4*>(dp + 4) = hi;
  }
}

// ---------------------------------------------------------------------------
// Flash-style causal attention, BQ=128 (wave = 32 queries), BK=64.
// K staged row-major [64 keys][128 dims] (full tile — R5 bug fixed);
// V^T staged [128][72] from global vT. P round-trips per-wave LDS
// (C->A layout). 2 barriers/tile. Balanced qt dispatch. Finite sentinels.
// ---------------------------------------------------------------------------
__global__ __launch_bounds__(256) void attn_fwd(const short* __restrict__ qb,
                                                const short* __restrict__ kb,
                                                const short* __restrict__ vT,
                                                short* __restrict__ out) {
  __shared__ __align__(16) short k_lds[64][136];   // 17.4 KB
  __shared__ __align__(16) short vt_lds[128][72];  // 18.4 KB
  __shared__ __align__(16) short p_lds[4][32][72]; // 18.4 KB

  const int tid = threadIdx.x, wave = tid >> 6, lane = tid & 63;
  const int quad = lane >> 4, l16 = lane & 15;
  const int bh = blockIdx.y;
  const int b = bh >> 4, h = bh & 15;
  const int kvh = h >> 2;
  // balanced dispatch: {15,0,14,1,...} pairs long+short blocks
  const int ii = blockIdx.x;
  const int qt = (ii & 1) ? (ii >> 1) : (15 - (ii >> 1));
  const int q0blk = qt * 128;
  const int q0 = q0blk + wave * 32;

  const short* qptr = qb + ((size_t)(b * NH + h) * S_LEN + q0) * HD;
  const short* kptr = kb + ((size_t)(b * NKV + kvh) * S_LEN) * HD;
  const short* vtp  = vT + ((size_t)(b * NKV + kvh) * HD) * S_LEN;

  // Q fragments: A-layout, m = l16 (+16 per m-subtile), k = st*32 + quad*8 + j
  f16x8 qf[2][4];
#pragma unroll
  for (int m = 0; m < 2; m++)
#pragma unroll
    for (int st = 0; st < 4; st++)
      qf[m][st] = *reinterpret_cast<const f16x8*>(
          qptr + (size_t)(m * 16 + l16) * HD + st * 32 + quad * 8);

  f32x4 o[2][8];
#pragma unroll
  for (int m = 0; m < 2; m++)
#pragma unroll
    for (int i = 0; i < 8; i++) o[m][i] = f32x4{0.f, 0.f, 0.f, 0.f};
  float m_i[2][4], l_i[2][4];
#pragma unroll
  for (int m = 0; m < 2; m++)
#pragma unroll
    for (int r = 0; r < 4; r++) { m_i[m][r] = NEG_SENT; l_i[m][r] = 0.f; }
  const float scale = 0.08838834764831845f;  // 1/sqrt(128)

  const int ktiles = (q0blk + 128) / 64;  // qt*2 + 2
  for (int kt = 0; kt < ktiles; kt++) {
    const int kbase = kt * 64;
    __syncthreads();
    // stage K [64 keys][128 dims]: 4 x (16 rows x 128 cols), coalesced b128
#pragma unroll
    for (int i = 0; i < 4; i++) {
      int r = (tid >> 4) + i * 16;   // key 0..63
      int c = (tid & 15) * 8;        // dim 0..120
      *reinterpret_cast<int4*>(&k_lds[r][c]) =
          *reinterpret_cast<const int4*>(kptr + (size_t)(kbase + r) * HD + c);
    }
    // stage V^T [128 dims][64 keys]: 4 x (32 rows x 64 cols), coalesced b128
#pragma unroll
    for (int i = 0; i < 4; i++) {
      int r = (tid >> 3) + i * 32;  // dim 0..127
      int c = (tid & 7) * 8;        // key 0..56
      *reinterpret_cast<int4*>(&vt_lds[r][c]) =
          *reinterpret_cast<const int4*>(vtp + (size_t)r * S_LEN + kbase + c);
    }
    __syncthreads();

    // S = Q K^T : 2 m-subtiles x 4 col-tiles of 16 keys
    f32x4 sc[2][4];
#pragma unroll
    for (int m = 0; m < 2; m++)
#pragma unroll
      for (int ct = 0; ct < 4; ct++) sc[m][ct] = f32x4{0.f, 0.f, 0.f, 0.f};
#pragma unroll
    for (int ct = 0; ct < 4; ct++) {
      f16x8 kf[4];
#pragma unroll
      for (int st = 0; st < 4; st++)
        kf[st] = *reinterpret_cast<const f16x8*>(&k_lds[ct * 16 + l16][st * 32 + quad * 8]);
#pragma unroll
      for (int m = 0; m < 2; m++)
#pragma unroll
        for (int st = 0; st < 4; st++)
          sc[m][ct] = __builtin_amdgcn_mfma_f32_16x16x32_f16(qf[m][st], kf[st], sc[m][ct], 0, 0, 0);
    }

    // mask + online softmax; C-layout row = quad*4+r, col = ct*16+l16
#pragma unroll
    for (int m = 0; m < 2; m++) {
      float rowmax[4] = {NEG_SENT, NEG_SENT, NEG_SENT, NEG_SENT};
#pragma unroll
      for (int ct = 0; ct < 4; ct++)
#pragma unroll
        for (int r = 0; r < 4; r++) {
          int qrow = q0 + m * 16 + quad * 4 + r;
          int col = kbase + ct * 16 + l16;
          float v = (col <= qrow) ? sc[m][ct][r] * scale : NEG_SENT;
          sc[m][ct][r] = v;
          rowmax[r] = fmaxf(rowmax[r], v);
        }
#pragma unroll
      for (int off = 1; off < 16; off <<= 1)
#pragma unroll
        for (int r = 0; r < 4; r++)
          rowmax[r] = fmaxf(rowmax[r], __shfl_xor(rowmax[r], off, 64));

      float alpha[4], rowsum[4] = {0.f, 0.f, 0.f, 0.f};
#pragma unroll
      for (int r = 0; r < 4; r++) {
        float mnew = fmaxf(m_i[m][r], rowmax[r]);
        alpha[r] = __expf(fminf(m_i[m][r] - mnew, 0.f));
        m_i[m][r] = mnew;
      }
#pragma unroll
      for (int ct = 0; ct < 4; ct++)
#pragma unroll
        for (int r = 0; r < 4; r++) {
          float p = __expf(fminf(sc[m][ct][r] - m_i[m][r], 0.f));
          if (sc[m][ct][r] == NEG_SENT) p = 0.f;
          rowsum[r] += p;
          p_lds[wave][m * 16 + quad * 4 + r][ct * 16 + l16] = f2h(p);
        }
#pragma unroll
      for (int off = 1; off < 16; off <<= 1)
#pragma unroll
        for (int r = 0; r < 4; r++) rowsum[r] += __shfl_xor(rowsum[r], off, 64);
#pragma unroll
      for (int r = 0; r < 4; r++) l_i[m][r] = l_i[m][r] * alpha[r] + rowsum[r];
#pragma unroll
      for (int nt = 0; nt < 8; nt++)
#pragma unroll
        for (int r = 0; r < 4; r++) o[m][nt][r] *= alpha[r];
    }

    // O += P V : p_lds is per-wave (same-wave LDS RAW handled by waitcnt).
    f16x8 pf[2][2];
#pragma unroll
    for (int m = 0; m < 2; m++) {
      pf[m][0] = *reinterpret_cast<const f16x8*>(&p_lds[wave][m * 16 + l16][quad * 8]);
      pf[m][1] = *reinterpret_cast<const f16x8*>(&p_lds[wave][m * 16 + l16][32 + quad * 8]);
    }
#pragma unroll
    for (int nt = 0; nt < 8; nt++) {
      f16x8 vf0 = *reinterpret_cast<const f16x8*>(&vt_lds[nt * 16 + l16][quad * 8]);
      f16x8 vf1 = *reinterpret_cast<const f16x8*>(&vt_lds[nt * 16 + l16][32 + quad * 8]);
#pragma unroll
      for (int m = 0; m < 2; m++) {
        o[m][nt] = __builtin_amdgcn_mfma_f32_16x16x32_f16(pf[m][0], vf0, o[m][nt], 0, 0, 0);
        o[m][nt] = __builtin_amdgcn_mfma_f32_16x16x32_f16(pf[m][1], vf1, o[m][nt], 0, 0, 0);
      }
    }
  }

#pragma unroll
  for (int m = 0; m < 2; m++)
#pragma unroll
    for (int r = 0; r < 4; r++) l_i[m][r] = 1.0f / fmaxf(l_i[m][r], 1e-20f);
#pragma unroll
  for (int m = 0; m < 2; m++)
#pragma unroll
    for (int nt = 0; nt < 8; nt++)
#pragma unroll
      for (int r = 0; r < 4; r++) {
        int srow = q0 + m * 16 + quad * 4 + r;
        int dcol = nt * 16 + l16;
        out[((size_t)(b * S_LEN + srow)) * DMODEL + h * HD + dcol] =
            f2h(o[m][nt][r] * l_i[m][r]);
      }
}

extern "C" void kernel_launch(void* const* d_in, const int* in_sizes, int n_in,
                              void* d_out, int out_size, void* d_ws, size_t ws_size,
                              hipStream_t stream) {
  const float* x      = (const float*)d_in[0];
  const float* q_w    = (const float*)d_in[1];
  const float* k_w    = (const float*)d_in[2];
  const float* v_w    = (const float*)d_in[3];
  const float* out_w  = (const float*)d_in[4];
  const float* q_gain = (const float*)d_in[5];
  float* out = (float*)d_out;

  const int BS = 2 * S_LEN;  // 4096 tokens
  // ws layout in fp16 shorts. attn aliases qraw (dead by then). Peak 84MB.
  short* xb   = (short*)d_ws;                    // 8M  (16MB)
  short* wqb  = xb   + (size_t)8 * 1024 * 1024;  // 4M
  short* wkb  = wqb  + (size_t)4 * 1024 * 1024;  // 1M
  short* wvb  = wkb  + (size_t)1 * 1024 * 1024;  // 1M
  short* wob  = wvb  + (size_t)1 * 1024 * 1024;  // 4M
  short* qraw = wob  + (size_t)4 * 1024 * 1024;  // 8M
  short* kraw = qraw + (size_t)8 * 1024 * 1024;  // 2M
  short* vraw = kraw + (size_t)2 * 1024 * 1024;  // 2M (token-major V)
  short* qbuf = vraw + (size_t)2 * 1024 * 1024;  // 8M
  short* kbuf = qbuf + (size_t)8 * 1024 * 1024;  // 2M
  short* vT   = kbuf + (size_t)2 * 1024 * 1024;  // 2M ([b][kv][dim][seq])
  short* attn = qraw;                            // alias

  dim3 blk(256);
  f32_to_f16<<<8192, blk, 0, stream>>>(x, xb, BS * DMODEL);
  f32_to_f16<<<4096, blk, 0, stream>>>(q_w, wqb, DMODEL * DMODEL);
  f32_to_f16<<<1024, blk, 0, stream>>>(k_w, wkb, 512 * DMODEL);
  f32_to_f16<<<1024, blk, 0, stream>>>(v_w, wvb, 512 * DMODEL);
  f32_to_f16<<<4096, blk, 0, stream>>>(out_w, wob, DMODEL * DMODEL);

  gemm_bt<false><<<dim3(32, 16), blk, 0, stream>>>(xb, wqb, qraw, 4096, 2048, 2048);
  gemm_bt<false><<<dim3(32, 4), blk, 0, stream>>>(xb, wkb, kraw, 4096, 512, 2048);
  gemm_bt<false><<<dim3(32, 4), blk, 0, stream>>>(xb, wvb, vraw, 4096, 512, 2048);

  postproc<<<dim3((BS * NH) / 4), blk, 0, stream>>>(qraw, qbuf, q_gain, NH, 2);
  postproc<<<dim3((BS * NKV) / 4), blk, 0, stream>>>(kraw, kbuf, q_gain, NKV, 1);
  v_transpose<<<dim3(BS / 64, 8), blk, 0, stream>>>(vraw, vT);

  attn_fwd<<<dim3(S_LEN / 128, 2 * NH), blk, 0, stream>>>(qbuf, kbuf, vT, attn);

  gemm_bt<true><<<dim3(32, 16), blk, 0, stream>>>(attn, wob, out, 4096, 2048, 2048);
}

// Round 7
// 444.106 us; speedup vs baseline: 1.6646x; 1.2029x over previous
//
#include <hip/hip_runtime.h>
#include <cmath>

// CausalSelfAttention fused pipeline, MI355X/gfx950.
// R7: attention load balance — pair-in-block (qt, 15-qt) => 256 uniform
// blocks of 34 k-tiles; double-buffered K/V staging (88KB LDS, 1 block/CU,
// 1 barrier/tile). GEMMs unchanged.

#define S_LEN 2048
#define DMODEL 2048
#define NH 16
#define NKV 4
#define HD 128

#define NEG_SENT -1.0e30f

typedef _Float16 f16x8 __attribute__((ext_vector_type(8)));
typedef float f32x4 __attribute__((ext_vector_type(4)));

static __device__ __forceinline__ short f2h(float f) {
  _Float16 h = (_Float16)f;
  return *(short*)&h;
}
static __device__ __forceinline__ float h2f(short s) {
  _Float16 h = *(_Float16*)&s;
  return (float)h;
}

// ---------------------------------------------------------------------------
// fp32 -> fp16 elementwise convert (n divisible by 4).
// ---------------------------------------------------------------------------
__global__ __launch_bounds__(256) void f32_to_f16(const float* __restrict__ src,
                                                  short* __restrict__ dst, int n) {
  int i = (blockIdx.x * 256 + threadIdx.x) * 4;
  if (i < n) {
    float4 v = *reinterpret_cast<const float4*>(src + i);
    short4 o;
    o.x = f2h(v.x); o.y = f2h(v.y); o.z = f2h(v.z); o.w = f2h(v.w);
    *reinterpret_cast<short4*>(dst + i) = o;
  }
}

// ---------------------------------------------------------------------------
// GEMM: C[M,N] = A[M,K] @ W[N,K]^T, fp16 in, fp32 accum, fp16 or fp32 out.
// ---------------------------------------------------------------------------
template <bool F32OUT>
__global__ __launch_bounds__(256) void gemm_bt(const short* __restrict__ A,
                                               const short* __restrict__ W,
                                               void* __restrict__ Cv,
                                               int M, int N, int K) {
  __shared__ __align__(16) short As[128][72];
  __shared__ __align__(16) short Ws[128][72];
  const int tid = threadIdx.x;
  const int wave = tid >> 6, lane = tid & 63;
  const int quad = lane >> 4, l16 = lane & 15;
  const int bm = blockIdx.x * 128, bn = blockIdx.y * 128;
  const int wm = (wave >> 1) * 64, wn = (wave & 1) * 64;

  f32x4 acc[4][4];
#pragma unroll
  for (int i = 0; i < 4; i++)
#pragma unroll
    for (int j = 0; j < 4; j++) acc[i][j] = f32x4{0.f, 0.f, 0.f, 0.f};

  const int lrow = tid >> 3;
  const int lcol = (tid & 7) * 8;

  for (int k0 = 0; k0 < K; k0 += 64) {
    __syncthreads();
#pragma unroll
    for (int i = 0; i < 4; i++) {
      int r = lrow + i * 32;
      *reinterpret_cast<int4*>(&As[r][lcol]) =
          *reinterpret_cast<const int4*>(A + (size_t)(bm + r) * K + k0 + lcol);
      *reinterpret_cast<int4*>(&Ws[r][lcol]) =
          *reinterpret_cast<const int4*>(W + (size_t)(bn + r) * K + k0 + lcol);
    }
    __syncthreads();
#pragma unroll
    for (int kk = 0; kk < 64; kk += 32) {
      f16x8 af[4], bfr[4];
#pragma unroll
      for (int mi = 0; mi < 4; mi++)
        af[mi] = *reinterpret_cast<const f16x8*>(&As[wm + mi * 16 + l16][kk + quad * 8]);
#pragma unroll
      for (int ni = 0; ni < 4; ni++)
        bfr[ni] = *reinterpret_cast<const f16x8*>(&Ws[wn + ni * 16 + l16][kk + quad * 8]);
#pragma unroll
      for (int mi = 0; mi < 4; mi++)
#pragma unroll
        for (int ni = 0; ni < 4; ni++)
          acc[mi][ni] = __builtin_amdgcn_mfma_f32_16x16x32_f16(af[mi], bfr[ni], acc[mi][ni], 0, 0, 0);
    }
  }
#pragma unroll
  for (int mi = 0; mi < 4; mi++)
#pragma unroll
    for (int ni = 0; ni < 4; ni++) {
      int gr = bm + wm + mi * 16 + quad * 4;
      int gc = bn + wn + ni * 16 + l16;
#pragma unroll
      for (int r = 0; r < 4; r++) {
        if (F32OUT)
          ((float*)Cv)[(size_t)(gr + r) * N + gc] = acc[mi][ni][r];
        else
          ((short*)Cv)[(size_t)(gr + r) * N + gc] = f2h(acc[mi][ni][r]);
      }
    }
}

// ---------------------------------------------------------------------------
// Per-(token,head) RMSNorm + partial RoPE + optional gain, relayout to
// [b][head][s][128]. mode: 1=norm+rope(k), 2=norm+rope+gain(q).
// ---------------------------------------------------------------------------
__global__ __launch_bounds__(256) void postproc(const short* __restrict__ src,
                                                short* __restrict__ dst,
                                                const float* __restrict__ gain,
                                                int n_heads, int mode) {
  int gw = blockIdx.x * 4 + (threadIdx.x >> 6);
  int lane = threadIdx.x & 63;
  int head = gw % n_heads;
  int token = gw / n_heads;
  int s = token & (S_LEN - 1);
  int b = token >> 11;
  const short* sp = src + (size_t)token * (n_heads * HD) + head * HD;
  float v0 = h2f(sp[lane]);
  float v1 = h2f(sp[lane + 64]);
  float ss = v0 * v0 + v1 * v1;
#pragma unroll
  for (int off = 1; off < 64; off <<= 1) ss += __shfl_xor(ss, off, 64);
  float sc = rsqrtf(ss * (1.0f / 128.0f) + 1.1920929e-07f);
  v0 *= sc;
  v1 *= sc;
  int i = lane & 31;
  float inv = powf(10000.0f, -((float)(2 * i) * (1.0f / 64.0f)));
  float f = (float)s * inv;
  float cs, sn;
  sincosf(f, &sn, &cs);
  float partner = __shfl_xor(v0, 32, 64);
  v0 = (lane < 32) ? (v0 * cs + partner * sn) : (v0 * cs - partner * sn);
  if (mode == 2) {
    float g = gain[head];
    v0 *= g;
    v1 *= g;
  }
  short* dp = dst + ((size_t)(b * n_heads + head) * S_LEN + s) * HD;
  dp[lane] = f2h(v0);
  dp[lane + 64] = f2h(v1);
}

// ---------------------------------------------------------------------------
// Tiled transpose: vraw[token][512] -> vT[b][kv][dim128][seq2048].
// ---------------------------------------------------------------------------
__global__ __launch_bounds__(256) void v_transpose(const short* __restrict__ src,
                                                   short* __restrict__ dst) {
  __shared__ __align__(16) short t[64][72];
  const int tid = threadIdx.x;
  const int s0 = blockIdx.x * 64;
  const int d0 = blockIdx.y * 64;
#pragma unroll
  for (int i = 0; i < 2; i++) {
    int r = (tid >> 3) + i * 32;
    int c = (tid & 7) * 8;
    *reinterpret_cast<int4*>(&t[r][c]) =
        *reinterpret_cast<const int4*>(src + (size_t)(s0 + r) * 512 + d0 + c);
  }
  __syncthreads();
  const int b = s0 >> 11;
  const int sbase = s0 & (S_LEN - 1);
#pragma unroll
  for (int i = 0; i < 2; i++) {
    int dr = (tid >> 3) + i * 32;
    int sc8 = (tid & 7) * 8;
    int d = d0 + dr;
    int kv = d >> 7, dw = d & 127;
    short4 lo, hi;
    lo.x = t[sc8 + 0][dr]; lo.y = t[sc8 + 1][dr];
    lo.z = t[sc8 + 2][dr]; lo.w = t[sc8 + 3][dr];
    hi.x = t[sc8 + 4][dr]; hi.y = t[sc8 + 5][dr];
    hi.z = t[sc8 + 6][dr]; hi.w = t[sc8 + 7][dr];
    short* dp = dst + (((size_t)(b * NKV + kv) * HD + dw) * S_LEN) + sbase + sc8;
    *reinterpret_cast<short4*>(dp) = lo;
    *reinterpret_cast<short4*>(dp + 4) = hi;
  }
}

// ---------------------------------------------------------------------------
// Flash-style causal attention, BQ=128 (wave = 32 queries), BK=64.
// Pair-in-block: block handles q-tiles {pair, 15-pair} sequentially =>
// all 256 blocks do exactly 34 k-tiles (perfect balance, 1 block/CU via
// 88KB LDS). Double-buffered K/V staging, 1 barrier/tile.
// ---------------------------------------------------------------------------
__global__ __launch_bounds__(256, 1) void attn_fwd(const short* __restrict__ qb,
                                                   const short* __restrict__ kb,
                                                   const short* __restrict__ vT,
                                                   short* __restrict__ out) {
  __shared__ __align__(16) short k_lds[2][64][136];   // 34.8 KB
  __shared__ __align__(16) short vt_lds[2][128][72];  // 36.9 KB
  __shared__ __align__(16) short p_lds[4][32][72];    // 18.4 KB

  const int tid = threadIdx.x, wave = tid >> 6, lane = tid & 63;
  const int quad = lane >> 4, l16 = lane & 15;
  const int bh = blockIdx.y;
  const int b = bh >> 4, h = bh & 15;
  const int kvh = h >> 2;
  const int pair = blockIdx.x;  // 0..7

  const short* kptr = kb + ((size_t)(b * NKV + kvh) * S_LEN) * HD;
  const short* vtp  = vT + ((size_t)(b * NKV + kvh) * HD) * S_LEN;
  const float scale = 0.08838834764831845f;  // 1/sqrt(128)

  const int kr = (tid >> 4), kc = (tid & 15) * 8;  // K staging coords
  const int vr = (tid >> 3), vc = (tid & 7) * 8;   // V^T staging coords

  for (int pass = 0; pass < 2; pass++) {
    const int qt = pass ? (15 - pair) : pair;
    const int q0blk = qt * 128;
    const int q0 = q0blk + wave * 32;
    const short* qptr = qb + ((size_t)(b * NH + h) * S_LEN + q0) * HD;

    // Q fragments: A-layout, m = l16 (+16 per subtile), k = st*32+quad*8+j
    f16x8 qf[2][4];
#pragma unroll
    for (int m = 0; m < 2; m++)
#pragma unroll
      for (int st = 0; st < 4; st++)
        qf[m][st] = *reinterpret_cast<const f16x8*>(
            qptr + (size_t)(m * 16 + l16) * HD + st * 32 + quad * 8);

    f32x4 o[2][8];
#pragma unroll
    for (int m = 0; m < 2; m++)
#pragma unroll
      for (int i = 0; i < 8; i++) o[m][i] = f32x4{0.f, 0.f, 0.f, 0.f};
    float m_i[2][4], l_i[2][4];
#pragma unroll
    for (int m = 0; m < 2; m++)
#pragma unroll
      for (int r = 0; r < 4; r++) { m_i[m][r] = NEG_SENT; l_i[m][r] = 0.f; }

    const int ktiles = qt * 2 + 2;

    // stage tile 0 into buffer 0
#pragma unroll
    for (int i = 0; i < 4; i++)
      *reinterpret_cast<int4*>(&k_lds[0][kr + i * 16][kc]) =
          *reinterpret_cast<const int4*>(kptr + (size_t)(kr + i * 16) * HD + kc);
#pragma unroll
    for (int i = 0; i < 4; i++)
      *reinterpret_cast<int4*>(&vt_lds[0][vr + i * 32][vc]) =
          *reinterpret_cast<const int4*>(vtp + (size_t)(vr + i * 32) * S_LEN + vc);
    __syncthreads();

    for (int kt = 0; kt < ktiles; kt++) {
      const int kbase = kt * 64;
      const int buf = kt & 1;
      // prefetch next tile into the other buffer (overlaps with compute)
      if (kt + 1 < ktiles) {
        const int nb = kbase + 64;
#pragma unroll
        for (int i = 0; i < 4; i++)
          *reinterpret_cast<int4*>(&k_lds[buf ^ 1][kr + i * 16][kc]) =
              *reinterpret_cast<const int4*>(kptr + (size_t)(nb + kr + i * 16) * HD + kc);
#pragma unroll
        for (int i = 0; i < 4; i++)
          *reinterpret_cast<int4*>(&vt_lds[buf ^ 1][vr + i * 32][vc]) =
              *reinterpret_cast<const int4*>(vtp + (size_t)(vr + i * 32) * S_LEN + nb + vc);
      }

      // S = Q K^T : 2 m-subtiles x 4 col-tiles of 16 keys
      f32x4 sc[2][4];
#pragma unroll
      for (int m = 0; m < 2; m++)
#pragma unroll
        for (int ct = 0; ct < 4; ct++) sc[m][ct] = f32x4{0.f, 0.f, 0.f, 0.f};
#pragma unroll
      for (int ct = 0; ct < 4; ct++) {
        f16x8 kf[4];
#pragma unroll
        for (int st = 0; st < 4; st++)
          kf[st] = *reinterpret_cast<const f16x8*>(&k_lds[buf][ct * 16 + l16][st * 32 + quad * 8]);
#pragma unroll
        for (int m = 0; m < 2; m++)
#pragma unroll
          for (int st = 0; st < 4; st++)
            sc[m][ct] = __builtin_amdgcn_mfma_f32_16x16x32_f16(qf[m][st], kf[st], sc[m][ct], 0, 0, 0);
      }

      // mask + online softmax; C-layout row = quad*4+r, col = ct*16+l16
#pragma unroll
      for (int m = 0; m < 2; m++) {
        float rowmax[4] = {NEG_SENT, NEG_SENT, NEG_SENT, NEG_SENT};
#pragma unroll
        for (int ct = 0; ct < 4; ct++)
#pragma unroll
          for (int r = 0; r < 4; r++) {
            int qrow = q0 + m * 16 + quad * 4 + r;
            int col = kbase + ct * 16 + l16;
            float v = (col <= qrow) ? sc[m][ct][r] * scale : NEG_SENT;
            sc[m][ct][r] = v;
            rowmax[r] = fmaxf(rowmax[r], v);
          }
#pragma unroll
        for (int off = 1; off < 16; off <<= 1)
#pragma unroll
          for (int r = 0; r < 4; r++)
            rowmax[r] = fmaxf(rowmax[r], __shfl_xor(rowmax[r], off, 64));

        float alpha[4], rowsum[4] = {0.f, 0.f, 0.f, 0.f};
#pragma unroll
        for (int r = 0; r < 4; r++) {
          float mnew = fmaxf(m_i[m][r], rowmax[r]);
          alpha[r] = __expf(fminf(m_i[m][r] - mnew, 0.f));
          m_i[m][r] = mnew;
        }
#pragma unroll
        for (int ct = 0; ct < 4; ct++)
#pragma unroll
          for (int r = 0; r < 4; r++) {
            float p = __expf(fminf(sc[m][ct][r] - m_i[m][r], 0.f));
            if (sc[m][ct][r] == NEG_SENT) p = 0.f;
            rowsum[r] += p;
            p_lds[wave][m * 16 + quad * 4 + r][ct * 16 + l16] = f2h(p);
          }
#pragma unroll
        for (int off = 1; off < 16; off <<= 1)
#pragma unroll
          for (int r = 0; r < 4; r++) rowsum[r] += __shfl_xor(rowsum[r], off, 64);
#pragma unroll
        for (int r = 0; r < 4; r++) l_i[m][r] = l_i[m][r] * alpha[r] + rowsum[r];
#pragma unroll
        for (int nt = 0; nt < 8; nt++)
#pragma unroll
          for (int r = 0; r < 4; r++) o[m][nt][r] *= alpha[r];
      }

      // O += P V : p_lds is per-wave (same-wave RAW via lgkmcnt)
      f16x8 pf[2][2];
#pragma unroll
      for (int m = 0; m < 2; m++) {
        pf[m][0] = *reinterpret_cast<const f16x8*>(&p_lds[wave][m * 16 + l16][quad * 8]);
        pf[m][1] = *reinterpret_cast<const f16x8*>(&p_lds[wave][m * 16 + l16][32 + quad * 8]);
      }
#pragma unroll
      for (int nt = 0; nt < 8; nt++) {
        f16x8 vf0 = *reinterpret_cast<const f16x8*>(&vt_lds[buf][nt * 16 + l16][quad * 8]);
        f16x8 vf1 = *reinterpret_cast<const f16x8*>(&vt_lds[buf][nt * 16 + l16][32 + quad * 8]);
#pragma unroll
        for (int m = 0; m < 2; m++) {
          o[m][nt] = __builtin_amdgcn_mfma_f32_16x16x32_f16(pf[m][0], vf0, o[m][nt], 0, 0, 0);
          o[m][nt] = __builtin_amdgcn_mfma_f32_16x16x32_f16(pf[m][1], vf1, o[m][nt], 0, 0, 0);
        }
      }
      __syncthreads();  // staged writes visible; buffer reads complete
    }

#pragma unroll
    for (int m = 0; m < 2; m++)
#pragma unroll
      for (int r = 0; r < 4; r++) l_i[m][r] = 1.0f / fmaxf(l_i[m][r], 1e-20f);
#pragma unroll
    for (int m = 0; m < 2; m++)
#pragma unroll
      for (int nt = 0; nt < 8; nt++)
#pragma unroll
        for (int r = 0; r < 4; r++) {
          int srow = q0 + m * 16 + quad * 4 + r;
          int dcol = nt * 16 + l16;
          out[((size_t)(b * S_LEN + srow)) * DMODEL + h * HD + dcol] =
              f2h(o[m][nt][r] * l_i[m][r]);
        }
  }
}

extern "C" void kernel_launch(void* const* d_in, const int* in_sizes, int n_in,
                              void* d_out, int out_size, void* d_ws, size_t ws_size,
                              hipStream_t stream) {
  const float* x      = (const float*)d_in[0];
  const float* q_w    = (const float*)d_in[1];
  const float* k_w    = (const float*)d_in[2];
  const float* v_w    = (const float*)d_in[3];
  const float* out_w  = (const float*)d_in[4];
  const float* q_gain = (const float*)d_in[5];
  float* out = (float*)d_out;

  const int BS = 2 * S_LEN;  // 4096 tokens
  short* xb   = (short*)d_ws;                    // 8M  (16MB)
  short* wqb  = xb   + (size_t)8 * 1024 * 1024;  // 4M
  short* wkb  = wqb  + (size_t)4 * 1024 * 1024;  // 1M
  short* wvb  = wkb  + (size_t)1 * 1024 * 1024;  // 1M
  short* wob  = wvb  + (size_t)1 * 1024 * 1024;  // 4M
  short* qraw = wob  + (size_t)4 * 1024 * 1024;  // 8M
  short* kraw = qraw + (size_t)8 * 1024 * 1024;  // 2M
  short* vraw = kraw + (size_t)2 * 1024 * 1024;  // 2M (token-major V)
  short* qbuf = vraw + (size_t)2 * 1024 * 1024;  // 8M
  short* kbuf = qbuf + (size_t)8 * 1024 * 1024;  // 2M
  short* vT   = kbuf + (size_t)2 * 1024 * 1024;  // 2M ([b][kv][dim][seq])
  short* attn = qraw;                            // alias

  dim3 blk(256);
  f32_to_f16<<<8192, blk, 0, stream>>>(x, xb, BS * DMODEL);
  f32_to_f16<<<4096, blk, 0, stream>>>(q_w, wqb, DMODEL * DMODEL);
  f32_to_f16<<<1024, blk, 0, stream>>>(k_w, wkb, 512 * DMODEL);
  f32_to_f16<<<1024, blk, 0, stream>>>(v_w, wvb, 512 * DMODEL);
  f32_to_f16<<<4096, blk, 0, stream>>>(out_w, wob, DMODEL * DMODEL);

  gemm_bt<false><<<dim3(32, 16), blk, 0, stream>>>(xb, wqb, qraw, 4096, 2048, 2048);
  gemm_bt<false><<<dim3(32, 4), blk, 0, stream>>>(xb, wkb, kraw, 4096, 512, 2048);
  gemm_bt<false><<<dim3(32, 4), blk, 0, stream>>>(xb, wvb, vraw, 4096, 512, 2048);

  postproc<<<dim3((BS * NH) / 4), blk, 0, stream>>>(qraw, qbuf, q_gain, NH, 2);
  postproc<<<dim3((BS * NKV) / 4), blk, 0, stream>>>(kraw, kbuf, q_gain, NKV, 1);
  v_transpose<<<dim3(BS / 64, 8), blk, 0, stream>>>(vraw, vT);

  attn_fwd<<<dim3(8, 2 * NH), blk, 0, stream>>>(qbuf, kbuf, vT, attn);

  gemm_bt<true><<<dim3(32, 16), blk, 0, stream>>>(attn, wob, out, 4096, 2048, 2048);
}

// Round 8
// 410.467 us; speedup vs baseline: 1.8011x; 1.0820x over previous
//
#include <hip/hip_runtime.h>
#include <cmath>

// CausalSelfAttention fused pipeline, MI355X/gfx950.
// R8: attention softmax diet — ones-column MFMA rowsum, scale folded into Q,
// fast path for full tiles, alpha-skip branch, 512 uniform blocks @ 2/CU
// (BQ=64 pair-in-block). GEMMs unchanged.

#define S_LEN 2048
#define DMODEL 2048
#define NH 16
#define NKV 4
#define HD 128

#define NEG_SENT -1.0e30f
#define QK_SCALE 0.08838834764831845f  // 1/sqrt(128), folded into Q

typedef _Float16 f16x8 __attribute__((ext_vector_type(8)));
typedef float f32x4 __attribute__((ext_vector_type(4)));

static __device__ __forceinline__ short f2h(float f) {
  _Float16 h = (_Float16)f;
  return *(short*)&h;
}
static __device__ __forceinline__ float h2f(short s) {
  _Float16 h = *(_Float16*)&s;
  return (float)h;
}

// ---------------------------------------------------------------------------
// fp32 -> fp16 elementwise convert (n divisible by 4).
// ---------------------------------------------------------------------------
__global__ __launch_bounds__(256) void f32_to_f16(const float* __restrict__ src,
                                                  short* __restrict__ dst, int n) {
  int i = (blockIdx.x * 256 + threadIdx.x) * 4;
  if (i < n) {
    float4 v = *reinterpret_cast<const float4*>(src + i);
    short4 o;
    o.x = f2h(v.x); o.y = f2h(v.y); o.z = f2h(v.z); o.w = f2h(v.w);
    *reinterpret_cast<short4*>(dst + i) = o;
  }
}

// ---------------------------------------------------------------------------
// GEMM: C[M,N] = A[M,K] @ W[N,K]^T, fp16 in, fp32 accum, fp16 or fp32 out.
// ---------------------------------------------------------------------------
template <bool F32OUT>
__global__ __launch_bounds__(256) void gemm_bt(const short* __restrict__ A,
                                               const short* __restrict__ W,
                                               void* __restrict__ Cv,
                                               int M, int N, int K) {
  __shared__ __align__(16) short As[128][72];
  __shared__ __align__(16) short Ws[128][72];
  const int tid = threadIdx.x;
  const int wave = tid >> 6, lane = tid & 63;
  const int quad = lane >> 4, l16 = lane & 15;
  const int bm = blockIdx.x * 128, bn = blockIdx.y * 128;
  const int wm = (wave >> 1) * 64, wn = (wave & 1) * 64;

  f32x4 acc[4][4];
#pragma unroll
  for (int i = 0; i < 4; i++)
#pragma unroll
    for (int j = 0; j < 4; j++) acc[i][j] = f32x4{0.f, 0.f, 0.f, 0.f};

  const int lrow = tid >> 3;
  const int lcol = (tid & 7) * 8;

  for (int k0 = 0; k0 < K; k0 += 64) {
    __syncthreads();
#pragma unroll
    for (int i = 0; i < 4; i++) {
      int r = lrow + i * 32;
      *reinterpret_cast<int4*>(&As[r][lcol]) =
          *reinterpret_cast<const int4*>(A + (size_t)(bm + r) * K + k0 + lcol);
      *reinterpret_cast<int4*>(&Ws[r][lcol]) =
          *reinterpret_cast<const int4*>(W + (size_t)(bn + r) * K + k0 + lcol);
    }
    __syncthreads();
#pragma unroll
    for (int kk = 0; kk < 64; kk += 32) {
      f16x8 af[4], bfr[4];
#pragma unroll
      for (int mi = 0; mi < 4; mi++)
        af[mi] = *reinterpret_cast<const f16x8*>(&As[wm + mi * 16 + l16][kk + quad * 8]);
#pragma unroll
      for (int ni = 0; ni < 4; ni++)
        bfr[ni] = *reinterpret_cast<const f16x8*>(&Ws[wn + ni * 16 + l16][kk + quad * 8]);
#pragma unroll
      for (int mi = 0; mi < 4; mi++)
#pragma unroll
        for (int ni = 0; ni < 4; ni++)
          acc[mi][ni] = __builtin_amdgcn_mfma_f32_16x16x32_f16(af[mi], bfr[ni], acc[mi][ni], 0, 0, 0);
    }
  }
#pragma unroll
  for (int mi = 0; mi < 4; mi++)
#pragma unroll
    for (int ni = 0; ni < 4; ni++) {
      int gr = bm + wm + mi * 16 + quad * 4;
      int gc = bn + wn + ni * 16 + l16;
#pragma unroll
      for (int r = 0; r < 4; r++) {
        if (F32OUT)
          ((float*)Cv)[(size_t)(gr + r) * N + gc] = acc[mi][ni][r];
        else
          ((short*)Cv)[(size_t)(gr + r) * N + gc] = f2h(acc[mi][ni][r]);
      }
    }
}

// ---------------------------------------------------------------------------
// Per-(token,head) RMSNorm + partial RoPE + optional gain, relayout to
// [b][head][s][128]. mode: 1=norm+rope(k), 2=norm+rope+gain*qk_scale(q).
// ---------------------------------------------------------------------------
__global__ __launch_bounds__(256) void postproc(const short* __restrict__ src,
                                                short* __restrict__ dst,
                                                const float* __restrict__ gain,
                                                int n_heads, int mode) {
  int gw = blockIdx.x * 4 + (threadIdx.x >> 6);
  int lane = threadIdx.x & 63;
  int head = gw % n_heads;
  int token = gw / n_heads;
  int s = token & (S_LEN - 1);
  int b = token >> 11;
  const short* sp = src + (size_t)token * (n_heads * HD) + head * HD;
  float v0 = h2f(sp[lane]);
  float v1 = h2f(sp[lane + 64]);
  float ss = v0 * v0 + v1 * v1;
#pragma unroll
  for (int off = 1; off < 64; off <<= 1) ss += __shfl_xor(ss, off, 64);
  float sc = rsqrtf(ss * (1.0f / 128.0f) + 1.1920929e-07f);
  v0 *= sc;
  v1 *= sc;
  int i = lane & 31;
  float inv = powf(10000.0f, -((float)(2 * i) * (1.0f / 64.0f)));
  float f = (float)s * inv;
  float cs, sn;
  sincosf(f, &sn, &cs);
  float partner = __shfl_xor(v0, 32, 64);
  v0 = (lane < 32) ? (v0 * cs + partner * sn) : (v0 * cs - partner * sn);
  if (mode == 2) {
    float g = gain[head] * QK_SCALE;  // fold 1/sqrt(d) into Q
    v0 *= g;
    v1 *= g;
  }
  short* dp = dst + ((size_t)(b * n_heads + head) * S_LEN + s) * HD;
  dp[lane] = f2h(v0);
  dp[lane + 64] = f2h(v1);
}

// ---------------------------------------------------------------------------
// Tiled transpose: vraw[token][512] -> vT[b][kv][dim128][seq2048].
// ---------------------------------------------------------------------------
__global__ __launch_bounds__(256) void v_transpose(const short* __restrict__ src,
                                                   short* __restrict__ dst) {
  __shared__ __align__(16) short t[64][72];
  const int tid = threadIdx.x;
  const int s0 = blockIdx.x * 64;
  const int d0 = blockIdx.y * 64;
#pragma unroll
  for (int i = 0; i < 2; i++) {
    int r = (tid >> 3) + i * 32;
    int c = (tid & 7) * 8;
    *reinterpret_cast<int4*>(&t[r][c]) =
        *reinterpret_cast<const int4*>(src + (size_t)(s0 + r) * 512 + d0 + c);
  }
  __syncthreads();
  const int b = s0 >> 11;
  const int sbase = s0 & (S_LEN - 1);
#pragma unroll
  for (int i = 0; i < 2; i++) {
    int dr = (tid >> 3) + i * 32;
    int sc8 = (tid & 7) * 8;
    int d = d0 + dr;
    int kv = d >> 7, dw = d & 127;
    short4 lo, hi;
    lo.x = t[sc8 + 0][dr]; lo.y = t[sc8 + 1][dr];
    lo.z = t[sc8 + 2][dr]; lo.w = t[sc8 + 3][dr];
    hi.x = t[sc8 + 4][dr]; hi.y = t[sc8 + 5][dr];
    hi.z = t[sc8 + 6][dr]; hi.w = t[sc8 + 7][dr];
    short* dp = dst + (((size_t)(b * NKV + kv) * HD + dw) * S_LEN) + sbase + sc8;
    *reinterpret_cast<short4*>(dp) = lo;
    *reinterpret_cast<short4*>(dp + 4) = hi;
  }
}

// ---------------------------------------------------------------------------
// Flash-style causal attention. Block = 4 waves; wave = 16 queries.
// Pair-in-block over BQ=64 sub-blocks: block j handles qsub {j, 31-j} =>
// 512 blocks x exactly 33 k-tiles; LDS 54.3KB caps residency at 2 blocks/CU
// (2 waves/SIMD). Rowsum via ones-column MFMA (o[8]); Q pre-scaled; fast
// path skips masking on all but the last tile; alpha-rescale skipped when
// the running max is unchanged.
// ---------------------------------------------------------------------------
__global__ __launch_bounds__(256, 2) void attn_fwd(const short* __restrict__ qb,
                                                   const short* __restrict__ kb,
                                                   const short* __restrict__ vT,
                                                   short* __restrict__ out) {
  __shared__ __align__(16) short k_lds[64][136];    // [key][dim]   17.4 KB
  __shared__ __align__(16) short vt_lds[144][72];   // [dim(+ones)][key] 20.7 KB
  __shared__ __align__(16) short p_lds[4][16][136]; // per-wave [q][key] 17.4 KB

  const int tid = threadIdx.x, wave = tid >> 6, lane = tid & 63;
  const int quad = lane >> 4, l16 = lane & 15;
  const int bh = blockIdx.y;
  const int b = bh >> 4, h = bh & 15;
  const int kvh = h >> 2;
  const int pj = blockIdx.x;  // 0..15

  const short* kptr = kb + ((size_t)(b * NKV + kvh) * S_LEN) * HD;
  const short* vtp  = vT + ((size_t)(b * NKV + kvh) * HD) * S_LEN;

  const int kr = (tid >> 4), kc = (tid & 15) * 8;  // K staging coords
  const int vr = (tid >> 3), vc = (tid & 7) * 8;   // V^T staging coords

  // ones-column rows (128 = ones, 129..143 = zeros), written once
  {
    int r = 128 + (tid >> 4);
    int c = (tid & 15) * 4;
    short val = (r == 128) ? (short)0x3C00 : (short)0;
    short4 v4 = {val, val, val, val};
    *reinterpret_cast<short4*>(&vt_lds[r][c]) = v4;
  }

  for (int pass = 0; pass < 2; pass++) {
    const int qsub = pass ? (31 - pj) : pj;       // 0..31
    const int q0 = qsub * 64 + wave * 16;          // wave's first query row
    const short* qptr = qb + ((size_t)(b * NH + h) * S_LEN + q0) * HD;

    // Q fragments: A-layout m=l16, k = st*32 + quad*8 + j (pre-scaled)
    f16x8 qf[4];
#pragma unroll
    for (int st = 0; st < 4; st++)
      qf[st] = *reinterpret_cast<const f16x8*>(
          qptr + (size_t)l16 * HD + st * 32 + quad * 8);

    f32x4 o[9];
#pragma unroll
    for (int i = 0; i < 9; i++) o[i] = f32x4{0.f, 0.f, 0.f, 0.f};
    float m_i[4] = {NEG_SENT, NEG_SENT, NEG_SENT, NEG_SENT};

    const int ktiles = qsub + 1;
    for (int kt = 0; kt < ktiles; kt++) {
      const int kbase = kt * 64;
      __syncthreads();  // prior-tile reads done
      // stage K [64 keys][128 dims]
#pragma unroll
      for (int i = 0; i < 4; i++)
        *reinterpret_cast<int4*>(&k_lds[kr + i * 16][kc]) =
            *reinterpret_cast<const int4*>(kptr + (size_t)(kbase + kr + i * 16) * HD + kc);
      // stage V^T [128 dims][64 keys]
#pragma unroll
      for (int i = 0; i < 4; i++)
        *reinterpret_cast<int4*>(&vt_lds[vr + i * 32][vc]) =
            *reinterpret_cast<const int4*>(vtp + (size_t)(vr + i * 32) * S_LEN + kbase + vc);
      __syncthreads();

      // S = Q K^T : 4 col-tiles of 16 keys (scores pre-scaled via Q)
      f32x4 sc[4];
#pragma unroll
      for (int ct = 0; ct < 4; ct++) sc[ct] = f32x4{0.f, 0.f, 0.f, 0.f};
#pragma unroll
      for (int ct = 0; ct < 4; ct++) {
#pragma unroll
        for (int st = 0; st < 4; st++) {
          f16x8 kf = *reinterpret_cast<const f16x8*>(&k_lds[ct * 16 + l16][st * 32 + quad * 8]);
          sc[ct] = __builtin_amdgcn_mfma_f32_16x16x32_f16(qf[st], kf, sc[ct], 0, 0, 0);
        }
      }

      // causal mask: only needed on the last tile (kbase+63 > q0 otherwise)
      if (kbase + 63 > q0) {
#pragma unroll
        for (int ct = 0; ct < 4; ct++)
#pragma unroll
          for (int r = 0; r < 4; r++) {
            int qrow = q0 + quad * 4 + r;
            int col = kbase + ct * 16 + l16;
            sc[ct][r] = (col <= qrow) ? sc[ct][r] : NEG_SENT;
          }
      }

      // online max (rowsum handled by ones-column MFMA)
      float cand[4];
#pragma unroll
      for (int r = 0; r < 4; r++)
        cand[r] = fmaxf(fmaxf(sc[0][r], sc[1][r]), fmaxf(sc[2][r], sc[3][r]));
#pragma unroll
      for (int off = 1; off < 16; off <<= 1)
#pragma unroll
        for (int r = 0; r < 4; r++)
          cand[r] = fmaxf(cand[r], __shfl_xor(cand[r], off, 64));

      bool ch = (cand[0] > m_i[0]) | (cand[1] > m_i[1]) |
                (cand[2] > m_i[2]) | (cand[3] > m_i[3]);
      if (__any(ch)) {
        float alpha[4];
#pragma unroll
        for (int r = 0; r < 4; r++) {
          float mn = fmaxf(m_i[r], cand[r]);
          alpha[r] = __expf(m_i[r] - mn);
          m_i[r] = mn;
        }
#pragma unroll
        for (int nt = 0; nt < 9; nt++)
#pragma unroll
          for (int r = 0; r < 4; r++) o[nt][r] *= alpha[r];
      }

      // p = exp(s - m); masked -> exp(-1e30) = 0 automatically
#pragma unroll
      for (int ct = 0; ct < 4; ct++)
#pragma unroll
        for (int r = 0; r < 4; r++) {
          float p = __expf(sc[ct][r] - m_i[r]);
          p_lds[wave][quad * 4 + r][ct * 16 + l16] = f2h(p);
        }

      // O += P V (nt=8 is the ones column -> running softmax denominator)
      f16x8 pf0 = *reinterpret_cast<const f16x8*>(&p_lds[wave][l16][quad * 8]);
      f16x8 pf1 = *reinterpret_cast<const f16x8*>(&p_lds[wave][l16][32 + quad * 8]);
#pragma unroll
      for (int nt = 0; nt < 9; nt++) {
        f16x8 vf0 = *reinterpret_cast<const f16x8*>(&vt_lds[nt * 16 + l16][quad * 8]);
        f16x8 vf1 = *reinterpret_cast<const f16x8*>(&vt_lds[nt * 16 + l16][32 + quad * 8]);
        o[nt] = __builtin_amdgcn_mfma_f32_16x16x32_f16(pf0, vf0, o[nt], 0, 0, 0);
        o[nt] = __builtin_amdgcn_mfma_f32_16x16x32_f16(pf1, vf1, o[nt], 0, 0, 0);
      }
    }

    // normalize: l for row quad*4+r sits in o[8][r] at lane quad*16 (col 0)
    float inv_l[4];
#pragma unroll
    for (int r = 0; r < 4; r++) {
      float l = __shfl(o[8][r], lane & 48, 64);
      inv_l[r] = 1.0f / fmaxf(l, 1e-20f);
    }
#pragma unroll
    for (int nt = 0; nt < 8; nt++)
#pragma unroll
      for (int r = 0; r < 4; r++) {
        int srow = q0 + quad * 4 + r;
        int dcol = nt * 16 + l16;
        out[((size_t)(b * S_LEN + srow)) * DMODEL + h * HD + dcol] =
            f2h(o[nt][r] * inv_l[r]);
      }
  }
}

extern "C" void kernel_launch(void* const* d_in, const int* in_sizes, int n_in,
                              void* d_out, int out_size, void* d_ws, size_t ws_size,
                              hipStream_t stream) {
  const float* x      = (const float*)d_in[0];
  const float* q_w    = (const float*)d_in[1];
  const float* k_w    = (const float*)d_in[2];
  const float* v_w    = (const float*)d_in[3];
  const float* out_w  = (const float*)d_in[4];
  const float* q_gain = (const float*)d_in[5];
  float* out = (float*)d_out;

  const int BS = 2 * S_LEN;  // 4096 tokens
  short* xb   = (short*)d_ws;                    // 8M  (16MB)
  short* wqb  = xb   + (size_t)8 * 1024 * 1024;  // 4M
  short* wkb  = wqb  + (size_t)4 * 1024 * 1024;  // 1M
  short* wvb  = wkb  + (size_t)1 * 1024 * 1024;  // 1M
  short* wob  = wvb  + (size_t)1 * 1024 * 1024;  // 4M
  short* qraw = wob  + (size_t)4 * 1024 * 1024;  // 8M
  short* kraw = qraw + (size_t)8 * 1024 * 1024;  // 2M
  short* vraw = kraw + (size_t)2 * 1024 * 1024;  // 2M (token-major V)
  short* qbuf = vraw + (size_t)2 * 1024 * 1024;  // 8M
  short* kbuf = qbuf + (size_t)8 * 1024 * 1024;  // 2M
  short* vT   = kbuf + (size_t)2 * 1024 * 1024;  // 2M ([b][kv][dim][seq])
  short* attn = qraw;                            // alias

  dim3 blk(256);
  f32_to_f16<<<8192, blk, 0, stream>>>(x, xb, BS * DMODEL);
  f32_to_f16<<<4096, blk, 0, stream>>>(q_w, wqb, DMODEL * DMODEL);
  f32_to_f16<<<1024, blk, 0, stream>>>(k_w, wkb, 512 * DMODEL);
  f32_to_f16<<<1024, blk, 0, stream>>>(v_w, wvb, 512 * DMODEL);
  f32_to_f16<<<4096, blk, 0, stream>>>(out_w, wob, DMODEL * DMODEL);

  gemm_bt<false><<<dim3(32, 16), blk, 0, stream>>>(xb, wqb, qraw, 4096, 2048, 2048);
  gemm_bt<false><<<dim3(32, 4), blk, 0, stream>>>(xb, wkb, kraw, 4096, 512, 2048);
  gemm_bt<false><<<dim3(32, 4), blk, 0, stream>>>(xb, wvb, vraw, 4096, 512, 2048);

  postproc<<<dim3((BS * NH) / 4), blk, 0, stream>>>(qraw, qbuf, q_gain, NH, 2);
  postproc<<<dim3((BS * NKV) / 4), blk, 0, stream>>>(kraw, kbuf, q_gain, NKV, 1);
  v_transpose<<<dim3(BS / 64, 8), blk, 0, stream>>>(vraw, vT);

  attn_fwd<<<dim3(16, 2 * NH), blk, 0, stream>>>(qbuf, kbuf, vT, attn);

  gemm_bt<true><<<dim3(32, 16), blk, 0, stream>>>(attn, wob, out, 4096, 2048, 2048);
}

// Round 9
// 387.100 us; speedup vs baseline: 1.9098x; 1.0604x over previous
//
#include <hip/hip_runtime.h>
#include <cmath>

// CausalSelfAttention fused pipeline, MI355X/gfx950.
// R9: GEMMs rebuilt in the m97 shape — global_load_lds width=16 staging
// (unpadded LDS, lane-contiguous), K/V projections fused into one 256-block
// launch via blockIdx.z. Attention unchanged from R8.

#define S_LEN 2048
#define DMODEL 2048
#define NH 16
#define NKV 4
#define HD 128

#define NEG_SENT -1.0e30f
#define QK_SCALE 0.08838834764831845f  // 1/sqrt(128), folded into Q

typedef _Float16 f16x8 __attribute__((ext_vector_type(8)));
typedef float f32x4 __attribute__((ext_vector_type(4)));

static __device__ __forceinline__ short f2h(float f) {
  _Float16 h = (_Float16)f;
  return *(short*)&h;
}
static __device__ __forceinline__ float h2f(short s) {
  _Float16 h = *(_Float16*)&s;
  return (float)h;
}

// async global->LDS, 16B per lane; lds dst = wave-uniform base + lane*16.
static __device__ __forceinline__ void stage16(const short* g, short* ldsbase) {
  __builtin_amdgcn_global_load_lds(
      (const __attribute__((address_space(1))) void*)g,
      (__attribute__((address_space(3))) void*)ldsbase, 16, 0, 0);
}

// ---------------------------------------------------------------------------
// fp32 -> fp16 elementwise convert (n divisible by 4).
// ---------------------------------------------------------------------------
__global__ __launch_bounds__(256) void f32_to_f16(const float* __restrict__ src,
                                                  short* __restrict__ dst, int n) {
  int i = (blockIdx.x * 256 + threadIdx.x) * 4;
  if (i < n) {
    float4 v = *reinterpret_cast<const float4*>(src + i);
    short4 o;
    o.x = f2h(v.x); o.y = f2h(v.y); o.z = f2h(v.z); o.w = f2h(v.w);
    *reinterpret_cast<short4*>(dst + i) = o;
  }
}

// ---------------------------------------------------------------------------
// GEMM core: C[M,N] = A[M,K] @ W[N,K]^T, fp16 in, fp32 accum.
// 128x128 tile, BK=64. Staging via global_load_lds_dwordx4: wave w stages
// rows {w*8 + i*32 + lane/8}, cols (lane&7)*8 — LDS is unpadded [128][64]
// so lane l lands at base + l*16B exactly (required by the instruction).
// ---------------------------------------------------------------------------
template <bool F32OUT>
static __device__ __forceinline__ void gemm_core(const short* __restrict__ A,
                                                 const short* __restrict__ W,
                                                 void* __restrict__ Cv,
                                                 int N, int K, int bm, int bn) {
  __shared__ __align__(16) short As[128][64];
  __shared__ __align__(16) short Ws[128][64];
  const int tid = threadIdx.x;
  const int wave = tid >> 6, lane = tid & 63;
  const int quad = lane >> 4, l16 = lane & 15;
  const int wm = (wave >> 1) * 64, wn = (wave & 1) * 64;

  f32x4 acc[4][4];
#pragma unroll
  for (int i = 0; i < 4; i++)
#pragma unroll
    for (int j = 0; j < 4; j++) acc[i][j] = f32x4{0.f, 0.f, 0.f, 0.f};

  const int srow = wave * 8 + (lane >> 3);  // staging row (this lane)
  const int scol = (lane & 7) * 8;          // staging col

  for (int k0 = 0; k0 < K; k0 += 64) {
    __syncthreads();  // prior compute done before overwrite
#pragma unroll
    for (int i = 0; i < 4; i++) {
      stage16(A + (size_t)(bm + srow + i * 32) * K + k0 + scol,
              &As[wave * 8 + i * 32][0]);
      stage16(W + (size_t)(bn + srow + i * 32) * K + k0 + scol,
              &Ws[wave * 8 + i * 32][0]);
    }
    __syncthreads();  // staging visible (vmcnt drained by compiler)
#pragma unroll
    for (int kk = 0; kk < 64; kk += 32) {
      f16x8 af[4], bfr[4];
#pragma unroll
      for (int mi = 0; mi < 4; mi++)
        af[mi] = *reinterpret_cast<const f16x8*>(&As[wm + mi * 16 + l16][kk + quad * 8]);
#pragma unroll
      for (int ni = 0; ni < 4; ni++)
        bfr[ni] = *reinterpret_cast<const f16x8*>(&Ws[wn + ni * 16 + l16][kk + quad * 8]);
#pragma unroll
      for (int mi = 0; mi < 4; mi++)
#pragma unroll
        for (int ni = 0; ni < 4; ni++)
          acc[mi][ni] = __builtin_amdgcn_mfma_f32_16x16x32_f16(af[mi], bfr[ni], acc[mi][ni], 0, 0, 0);
    }
  }
  // C/D layout: row = quad*4 + r, col = l16
#pragma unroll
  for (int mi = 0; mi < 4; mi++)
#pragma unroll
    for (int ni = 0; ni < 4; ni++) {
      int gr = bm + wm + mi * 16 + quad * 4;
      int gc = bn + wn + ni * 16 + l16;
#pragma unroll
      for (int r = 0; r < 4; r++) {
        if (F32OUT)
          ((float*)Cv)[(size_t)(gr + r) * N + gc] = acc[mi][ni][r];
        else
          ((short*)Cv)[(size_t)(gr + r) * N + gc] = f2h(acc[mi][ni][r]);
      }
    }
}

template <bool F32OUT>
__global__ __launch_bounds__(256) void gemm_bt(const short* __restrict__ A,
                                               const short* __restrict__ W,
                                               void* __restrict__ Cv,
                                               int N, int K) {
  gemm_core<F32OUT>(A, W, Cv, N, K, blockIdx.x * 128, blockIdx.y * 128);
}

// K and V projections fused: blockIdx.z selects (W, C). Grid (32,4,2) = 256.
__global__ __launch_bounds__(256) void gemm_kv(const short* __restrict__ A,
                                               const short* __restrict__ W0,
                                               const short* __restrict__ W1,
                                               short* __restrict__ C0,
                                               short* __restrict__ C1,
                                               int N, int K) {
  const short* W = blockIdx.z ? W1 : W0;
  short* C = blockIdx.z ? C1 : C0;
  gemm_core<false>(A, W, (void*)C, N, K, blockIdx.x * 128, blockIdx.y * 128);
}

// ---------------------------------------------------------------------------
// Per-(token,head) RMSNorm + partial RoPE + optional gain, relayout to
// [b][head][s][128]. mode: 1=norm+rope(k), 2=norm+rope+gain*qk_scale(q).
// ---------------------------------------------------------------------------
__global__ __launch_bounds__(256) void postproc(const short* __restrict__ src,
                                                short* __restrict__ dst,
                                                const float* __restrict__ gain,
                                                int n_heads, int mode) {
  int gw = blockIdx.x * 4 + (threadIdx.x >> 6);
  int lane = threadIdx.x & 63;
  int head = gw % n_heads;
  int token = gw / n_heads;
  int s = token & (S_LEN - 1);
  int b = token >> 11;
  const short* sp = src + (size_t)token * (n_heads * HD) + head * HD;
  float v0 = h2f(sp[lane]);
  float v1 = h2f(sp[lane + 64]);
  float ss = v0 * v0 + v1 * v1;
#pragma unroll
  for (int off = 1; off < 64; off <<= 1) ss += __shfl_xor(ss, off, 64);
  float sc = rsqrtf(ss * (1.0f / 128.0f) + 1.1920929e-07f);
  v0 *= sc;
  v1 *= sc;
  int i = lane & 31;
  float inv = powf(10000.0f, -((float)(2 * i) * (1.0f / 64.0f)));
  float f = (float)s * inv;
  float cs, sn;
  sincosf(f, &sn, &cs);
  float partner = __shfl_xor(v0, 32, 64);
  v0 = (lane < 32) ? (v0 * cs + partner * sn) : (v0 * cs - partner * sn);
  if (mode == 2) {
    float g = gain[head] * QK_SCALE;  // fold 1/sqrt(d) into Q
    v0 *= g;
    v1 *= g;
  }
  short* dp = dst + ((size_t)(b * n_heads + head) * S_LEN + s) * HD;
  dp[lane] = f2h(v0);
  dp[lane + 64] = f2h(v1);
}

// ---------------------------------------------------------------------------
// Tiled transpose: vraw[token][512] -> vT[b][kv][dim128][seq2048].
// ---------------------------------------------------------------------------
__global__ __launch_bounds__(256) void v_transpose(const short* __restrict__ src,
                                                   short* __restrict__ dst) {
  __shared__ __align__(16) short t[64][72];
  const int tid = threadIdx.x;
  const int s0 = blockIdx.x * 64;
  const int d0 = blockIdx.y * 64;
#pragma unroll
  for (int i = 0; i < 2; i++) {
    int r = (tid >> 3) + i * 32;
    int c = (tid & 7) * 8;
    *reinterpret_cast<int4*>(&t[r][c]) =
        *reinterpret_cast<const int4*>(src + (size_t)(s0 + r) * 512 + d0 + c);
  }
  __syncthreads();
  const int b = s0 >> 11;
  const int sbase = s0 & (S_LEN - 1);
#pragma unroll
  for (int i = 0; i < 2; i++) {
    int dr = (tid >> 3) + i * 32;
    int sc8 = (tid & 7) * 8;
    int d = d0 + dr;
    int kv = d >> 7, dw = d & 127;
    short4 lo, hi;
    lo.x = t[sc8 + 0][dr]; lo.y = t[sc8 + 1][dr];
    lo.z = t[sc8 + 2][dr]; lo.w = t[sc8 + 3][dr];
    hi.x = t[sc8 + 4][dr]; hi.y = t[sc8 + 5][dr];
    hi.z = t[sc8 + 6][dr]; hi.w = t[sc8 + 7][dr];
    short* dp = dst + (((size_t)(b * NKV + kv) * HD + dw) * S_LEN) + sbase + sc8;
    *reinterpret_cast<short4*>(dp) = lo;
    *reinterpret_cast<short4*>(dp + 4) = hi;
  }
}

// ---------------------------------------------------------------------------
// Flash-style causal attention (unchanged from R8). Block = 4 waves;
// wave = 16 queries; pair-in-block over BQ=64 sub-blocks (512 uniform
// blocks, 2/CU). Rowsum via ones-column MFMA; Q pre-scaled; fast-path
// masking; alpha-skip.
// ---------------------------------------------------------------------------
__global__ __launch_bounds__(256, 2) void attn_fwd(const short* __restrict__ qb,
                                                   const short* __restrict__ kb,
                                                   const short* __restrict__ vT,
                                                   short* __restrict__ out) {
  __shared__ __align__(16) short k_lds[64][136];
  __shared__ __align__(16) short vt_lds[144][72];
  __shared__ __align__(16) short p_lds[4][16][136];

  const int tid = threadIdx.x, wave = tid >> 6, lane = tid & 63;
  const int quad = lane >> 4, l16 = lane & 15;
  const int bh = blockIdx.y;
  const int b = bh >> 4, h = bh & 15;
  const int kvh = h >> 2;
  const int pj = blockIdx.x;  // 0..15

  const short* kptr = kb + ((size_t)(b * NKV + kvh) * S_LEN) * HD;
  const short* vtp  = vT + ((size_t)(b * NKV + kvh) * HD) * S_LEN;

  const int kr = (tid >> 4), kc = (tid & 15) * 8;
  const int vr = (tid >> 3), vc = (tid & 7) * 8;

  {
    int r = 128 + (tid >> 4);
    int c = (tid & 15) * 4;
    short val = (r == 128) ? (short)0x3C00 : (short)0;
    short4 v4 = {val, val, val, val};
    *reinterpret_cast<short4*>(&vt_lds[r][c]) = v4;
  }

  for (int pass = 0; pass < 2; pass++) {
    const int qsub = pass ? (31 - pj) : pj;
    const int q0 = qsub * 64 + wave * 16;
    const short* qptr = qb + ((size_t)(b * NH + h) * S_LEN + q0) * HD;

    f16x8 qf[4];
#pragma unroll
    for (int st = 0; st < 4; st++)
      qf[st] = *reinterpret_cast<const f16x8*>(
          qptr + (size_t)l16 * HD + st * 32 + quad * 8);

    f32x4 o[9];
#pragma unroll
    for (int i = 0; i < 9; i++) o[i] = f32x4{0.f, 0.f, 0.f, 0.f};
    float m_i[4] = {NEG_SENT, NEG_SENT, NEG_SENT, NEG_SENT};

    const int ktiles = qsub + 1;
    for (int kt = 0; kt < ktiles; kt++) {
      const int kbase = kt * 64;
      __syncthreads();
#pragma unroll
      for (int i = 0; i < 4; i++)
        *reinterpret_cast<int4*>(&k_lds[kr + i * 16][kc]) =
            *reinterpret_cast<const int4*>(kptr + (size_t)(kbase + kr + i * 16) * HD + kc);
#pragma unroll
      for (int i = 0; i < 4; i++)
        *reinterpret_cast<int4*>(&vt_lds[vr + i * 32][vc]) =
            *reinterpret_cast<const int4*>(vtp + (size_t)(vr + i * 32) * S_LEN + kbase + vc);
      __syncthreads();

      f32x4 sc[4];
#pragma unroll
      for (int ct = 0; ct < 4; ct++) sc[ct] = f32x4{0.f, 0.f, 0.f, 0.f};
#pragma unroll
      for (int ct = 0; ct < 4; ct++) {
#pragma unroll
        for (int st = 0; st < 4; st++) {
          f16x8 kf = *reinterpret_cast<const f16x8*>(&k_lds[ct * 16 + l16][st * 32 + quad * 8]);
          sc[ct] = __builtin_amdgcn_mfma_f32_16x16x32_f16(qf[st], kf, sc[ct], 0, 0, 0);
        }
      }

      if (kbase + 63 > q0) {
#pragma unroll
        for (int ct = 0; ct < 4; ct++)
#pragma unroll
          for (int r = 0; r < 4; r++) {
            int qrow = q0 + quad * 4 + r;
            int col = kbase + ct * 16 + l16;
            sc[ct][r] = (col <= qrow) ? sc[ct][r] : NEG_SENT;
          }
      }

      float cand[4];
#pragma unroll
      for (int r = 0; r < 4; r++)
        cand[r] = fmaxf(fmaxf(sc[0][r], sc[1][r]), fmaxf(sc[2][r], sc[3][r]));
#pragma unroll
      for (int off = 1; off < 16; off <<= 1)
#pragma unroll
        for (int r = 0; r < 4; r++)
          cand[r] = fmaxf(cand[r], __shfl_xor(cand[r], off, 64));

      bool ch = (cand[0] > m_i[0]) | (cand[1] > m_i[1]) |
                (cand[2] > m_i[2]) | (cand[3] > m_i[3]);
      if (__any(ch)) {
        float alpha[4];
#pragma unroll
        for (int r = 0; r < 4; r++) {
          float mn = fmaxf(m_i[r], cand[r]);
          alpha[r] = __expf(m_i[r] - mn);
          m_i[r] = mn;
        }
#pragma unroll
        for (int nt = 0; nt < 9; nt++)
#pragma unroll
          for (int r = 0; r < 4; r++) o[nt][r] *= alpha[r];
      }

#pragma unroll
      for (int ct = 0; ct < 4; ct++)
#pragma unroll
        for (int r = 0; r < 4; r++) {
          float p = __expf(sc[ct][r] - m_i[r]);
          p_lds[wave][quad * 4 + r][ct * 16 + l16] = f2h(p);
        }

      f16x8 pf0 = *reinterpret_cast<const f16x8*>(&p_lds[wave][l16][quad * 8]);
      f16x8 pf1 = *reinterpret_cast<const f16x8*>(&p_lds[wave][l16][32 + quad * 8]);
#pragma unroll
      for (int nt = 0; nt < 9; nt++) {
        f16x8 vf0 = *reinterpret_cast<const f16x8*>(&vt_lds[nt * 16 + l16][quad * 8]);
        f16x8 vf1 = *reinterpret_cast<const f16x8*>(&vt_lds[nt * 16 + l16][32 + quad * 8]);
        o[nt] = __builtin_amdgcn_mfma_f32_16x16x32_f16(pf0, vf0, o[nt], 0, 0, 0);
        o[nt] = __builtin_amdgcn_mfma_f32_16x16x32_f16(pf1, vf1, o[nt], 0, 0, 0);
      }
    }

    float inv_l[4];
#pragma unroll
    for (int r = 0; r < 4; r++) {
      float l = __shfl(o[8][r], lane & 48, 64);
      inv_l[r] = 1.0f / fmaxf(l, 1e-20f);
    }
#pragma unroll
    for (int nt = 0; nt < 8; nt++)
#pragma unroll
      for (int r = 0; r < 4; r++) {
        int srow = q0 + quad * 4 + r;
        int dcol = nt * 16 + l16;
        out[((size_t)(b * S_LEN + srow)) * DMODEL + h * HD + dcol] =
            f2h(o[nt][r] * inv_l[r]);
      }
  }
}

extern "C" void kernel_launch(void* const* d_in, const int* in_sizes, int n_in,
                              void* d_out, int out_size, void* d_ws, size_t ws_size,
                              hipStream_t stream) {
  const float* x      = (const float*)d_in[0];
  const float* q_w    = (const float*)d_in[1];
  const float* k_w    = (const float*)d_in[2];
  const float* v_w    = (const float*)d_in[3];
  const float* out_w  = (const float*)d_in[4];
  const float* q_gain = (const float*)d_in[5];
  float* out = (float*)d_out;

  const int BS = 2 * S_LEN;  // 4096 tokens
  short* xb   = (short*)d_ws;                    // 8M  (16MB)
  short* wqb  = xb   + (size_t)8 * 1024 * 1024;  // 4M
  short* wkb  = wqb  + (size_t)4 * 1024 * 1024;  // 1M
  short* wvb  = wkb  + (size_t)1 * 1024 * 1024;  // 1M
  short* wob  = wvb  + (size_t)1 * 1024 * 1024;  // 4M
  short* qraw = wob  + (size_t)4 * 1024 * 1024;  // 8M
  short* kraw = qraw + (size_t)8 * 1024 * 1024;  // 2M
  short* vraw = kraw + (size_t)2 * 1024 * 1024;  // 2M (token-major V)
  short* qbuf = vraw + (size_t)2 * 1024 * 1024;  // 8M
  short* kbuf = qbuf + (size_t)8 * 1024 * 1024;  // 2M
  short* vT   = kbuf + (size_t)2 * 1024 * 1024;  // 2M ([b][kv][dim][seq])
  short* attn = qraw;                            // alias

  dim3 blk(256);
  f32_to_f16<<<8192, blk, 0, stream>>>(x, xb, BS * DMODEL);
  f32_to_f16<<<4096, blk, 0, stream>>>(q_w, wqb, DMODEL * DMODEL);
  f32_to_f16<<<1024, blk, 0, stream>>>(k_w, wkb, 512 * DMODEL);
  f32_to_f16<<<1024, blk, 0, stream>>>(v_w, wvb, 512 * DMODEL);
  f32_to_f16<<<4096, blk, 0, stream>>>(out_w, wob, DMODEL * DMODEL);

  gemm_bt<false><<<dim3(32, 16), blk, 0, stream>>>(xb, wqb, qraw, 2048, 2048);
  gemm_kv<<<dim3(32, 4, 2), blk, 0, stream>>>(xb, wkb, wvb, kraw, vraw, 512, 2048);

  postproc<<<dim3((BS * NH) / 4), blk, 0, stream>>>(qraw, qbuf, q_gain, NH, 2);
  postproc<<<dim3((BS * NKV) / 4), blk, 0, stream>>>(kraw, kbuf, q_gain, NKV, 1);
  v_transpose<<<dim3(BS / 64, 8), blk, 0, stream>>>(vraw, vT);

  attn_fwd<<<dim3(16, 2 * NH), blk, 0, stream>>>(qbuf, kbuf, vT, attn);

  gemm_bt<true><<<dim3(32, 16), blk, 0, stream>>>(attn, wob, out, 2048, 2048);
}